// Round 3
// baseline (3049.151 us; speedup 1.0000x reference)
//
#include <hip/hip_runtime.h>
#include <hip/hip_bf16.h>
#include <math.h>

typedef __bf16 bf16x8 __attribute__((ext_vector_type(8)));
typedef float f32x4 __attribute__((ext_vector_type(4)));
typedef unsigned short u16x8 __attribute__((ext_vector_type(8)));

__device__ inline unsigned short f2b(float f) {
  union { float f; unsigned u; } v; v.f = f;
  unsigned u = v.u;
  return (unsigned short)((u + 0x7fffu + ((u >> 16) & 1u)) >> 16);
}
__device__ inline float b2f(unsigned short s) {
  union { unsigned u; float f; } v; v.u = ((unsigned)s) << 16;
  return v.f;
}
__device__ inline float sigm(float x) { return 1.f / (1.f + __expf(-x)); }
__device__ inline float tanh_f(float x) {
  float e = __expf(2.f * x);
  return 1.f - 2.f / (e + 1.f);
}
__device__ inline void gll16(const unsigned short* g, unsigned short* l) {
  __builtin_amdgcn_global_load_lds(
      (const __attribute__((address_space(1))) void*)g,
      (__attribute__((address_space(3))) void*)l, 16, 0, 0);
}

// -------------------- prep: weights->bf16, h init --------------------
__global__ __launch_bounds__(256) void prep_kernel(
    const float* __restrict__ Wih, const float* __restrict__ Whh,
    const float* __restrict__ c, unsigned short* __restrict__ Wihb,
    unsigned short* __restrict__ Whhb, unsigned short* __restrict__ hbf,
    float* __restrict__ h32, long nW, long nH)
{
  long stride = (long)gridDim.x * blockDim.x;
  long t0 = (long)blockIdx.x * blockDim.x + threadIdx.x;
  for (long i = t0; i < nW; i += stride) {
    Wihb[i] = f2b(Wih[i]);
    Whhb[i] = f2b(Whh[i]);
  }
  for (long i = t0; i < nH; i += stride) {
    float v = c[i];
    h32[i] = v;
    hbf[i] = f2b(v);
  }
}

// -------------------- transpose x (B,E,K) -> XS (K,B,E) bf16 ----------
__global__ __launch_bounds__(256) void transpose_x(
    const float* __restrict__ x, unsigned short* __restrict__ XS,
    int B, int E, int K)
{
  __shared__ float T[64][65];
  int e0 = blockIdx.x * 64;
  int b = blockIdx.y;
  int t = threadIdx.x;
  const float* xb = x + ((long)b * E + e0) * K;
#pragma unroll
  for (int i = 0; i < 4; ++i) {
    int cidx = i * 256 + t;
    int e = cidx >> 4;
    int f4 = cidx & 15;
    float4 v = *(const float4*)(xb + (long)e * K + f4 * 4);
    T[e][f4 * 4 + 0] = v.x;
    T[e][f4 * 4 + 1] = v.y;
    T[e][f4 * 4 + 2] = v.z;
    T[e][f4 * 4 + 3] = v.w;
  }
  __syncthreads();
#pragma unroll
  for (int i = 0; i < 16; ++i) {
    int cidx = i * 256 + t;
    int k = cidx >> 6;
    int e = cidx & 63;
    if (k < K - 1)
      XS[((long)(k + 1) * B + b) * E + e0 + e] = f2b(T[e][k]);
  }
}

// -------------------- GEMM: C(M,N) = A(M,K) @ Bw(N,K)^T + bias --------
#define BM 128
#define BN 128
#define BKS 64

template<int OUTBF>
__global__ __launch_bounds__(256)
void gemm_bt(const unsigned short* __restrict__ A,
             const unsigned short* __restrict__ Bw,
             const float* __restrict__ bias,
             float* __restrict__ Cf, unsigned short* __restrict__ Cb,
             int M, int N, int K)
{
  __shared__ __align__(16) unsigned short As[BM * BKS];
  __shared__ __align__(16) unsigned short Bs[BN * BKS];

  int nwg = gridDim.x * gridDim.y;
  int wg = blockIdx.y * gridDim.x + blockIdx.x;
  if ((nwg & 7) == 0) { int ch = nwg >> 3; wg = (wg & 7) * ch + (wg >> 3); }
  int tx = wg % gridDim.x;
  int ty = wg / gridDim.x;

  const int tid = threadIdx.x;
  const int lane = tid & 63;
  const int wave = tid >> 6;
  const int wr = wave >> 1, wc = wave & 1;

  f32x4 acc[4][4] = {};

  const long a_base = (long)ty * BM * K;
  const long b_base = (long)tx * BN * K;

  for (int kt = 0; kt < K; kt += BKS) {
    __syncthreads();
#pragma unroll
    for (int i = 0; i < 4; ++i) {
      int c = i * 256 + tid;
      int row = c >> 3, sc = c & 7;
      int gcol8 = sc ^ (row & 7);
      const unsigned short* ga = A + a_base + (long)row * K + kt + gcol8 * 8;
      const unsigned short* gb = Bw + b_base + (long)row * K + kt + gcol8 * 8;
      int cbase = (i * 256 + wave * 64) * 8;
      gll16(ga, &As[cbase]);
      gll16(gb, &Bs[cbase]);
    }
    __syncthreads();
#pragma unroll
    for (int kk = 0; kk < BKS; kk += 32) {
      int kidx = kk + ((lane >> 4) << 3);
      int c8 = kidx >> 3;
      bf16x8 af[4], bfv[4];
#pragma unroll
      for (int m = 0; m < 4; ++m) {
        int row = wr * 64 + m * 16 + (lane & 15);
        af[m] = *(const bf16x8*)&As[row * BKS + ((c8 ^ (row & 7)) << 3)];
      }
#pragma unroll
      for (int n = 0; n < 4; ++n) {
        int col = wc * 64 + n * 16 + (lane & 15);
        bfv[n] = *(const bf16x8*)&Bs[col * BKS + ((c8 ^ (col & 7)) << 3)];
      }
#pragma unroll
      for (int m = 0; m < 4; ++m)
#pragma unroll
        for (int n = 0; n < 4; ++n)
          acc[m][n] = __builtin_amdgcn_mfma_f32_16x16x32_bf16(
              af[m], bfv[n], acc[m][n], 0, 0, 0);
    }
  }

  long crow0 = (long)ty * BM + wr * 64;
  long ccol0 = (long)tx * BN + wc * 64;
#pragma unroll
  for (int m = 0; m < 4; ++m) {
#pragma unroll
    for (int n = 0; n < 4; ++n) {
      long col = ccol0 + n * 16 + (lane & 15);
      float bv = bias[col];
#pragma unroll
      for (int j = 0; j < 4; ++j) {
        long row = crow0 + m * 16 + ((lane >> 4) << 2) + j;
        float v = acc[m][n][j] + bv;
        if (OUTBF) Cb[row * N + col] = f2b(v);
        else       Cf[row * N + col] = v;
      }
    }
  }
}

// -------------------- persistent fused recurrence v2 ------------------
// 256 WGs x 256 threads (4 waves), WG (bt,et) owns 64(b) x 64(e) tile.
// Wave w owns e-cols [16w,16w+16) for ALL 3 gates -> gates in-register,
// h held in 16 VGPRs across all steps. 3-buffer K-loop, 1 barrier/tile,
// counted vmcnt(8). GI via coalesced LDS stage; Y via LDS bounce.
__global__ __launch_bounds__(256, 1)
void gru_rec2(const unsigned short* __restrict__ GI,
              const unsigned short* __restrict__ Whhb,
              const float* __restrict__ bhh,
              const float* __restrict__ c0,
              unsigned short* __restrict__ hbuf0,
              unsigned short* __restrict__ hbuf1,
              unsigned short* __restrict__ Y,
              unsigned int* __restrict__ bar,
              int B, int E, int K, int net)
{
  __shared__ __align__(16) unsigned short As[3][4096];    // 64x64 bf16 x3
  __shared__ __align__(16) unsigned short Bs[3][12288];   // 192x64 bf16 x3
  __shared__ __align__(16) unsigned short GIs[12288];     // 64x192 bf16
  __shared__ __align__(16) unsigned short Ys[64 * 72];    // 64x64 padded

  const int N3 = 3 * E;
  const int NKT = E >> 6;
  const int wg = blockIdx.x;
  const int bt = wg / net;
  const int et = wg - bt * net;
  const int b0 = bt << 6;
  const int e0 = et << 6;
  const int tid = threadIdx.x;
  const int lane = tid & 63;
  const int q = lane >> 4;
  const int el = ((tid >> 6) << 4) + (lane & 15);  // 0..63, wave-partitioned
  const int axsh = lane & 7;

  // ---- staging offsets (elements) ----
  long a_goff[2];
#pragma unroll
  for (int i = 0; i < 2; ++i) {
    int cgl = i * 256 + tid;
    int row = cgl >> 3;
    int g8 = (cgl & 7) ^ (row & 7);
    a_goff[i] = (long)(b0 + row) * E + g8 * 8;
  }
  long b_goff[6];
#pragma unroll
  for (int i = 0; i < 6; ++i) {
    int cgl = i * 256 + tid;
    int row = cgl >> 3;
    int g8 = (cgl & 7) ^ (row & 7);
    long wrow = (long)(row >> 6) * E + e0 + (row & 63);
    b_goff[i] = wrow * E + g8 * 8;
  }
  long gi_goff[6];
#pragma unroll
  for (int i = 0; i < 6; ++i) {
    int cgl = i * 256 + tid;
    int row = cgl / 24;
    int cc = cgl - row * 24;
    gi_goff[i] = (long)(b0 + row) * N3 + (long)(cc >> 3) * E + e0 + (cc & 7) * 8;
  }

  // ---- persistent per-lane state: h fp32, bhh ----
  float hreg[4][4];
#pragma unroll
  for (int m = 0; m < 4; ++m)
#pragma unroll
    for (int j = 0; j < 4; ++j)
      hreg[m][j] = c0[(long)(b0 + m * 16 + q * 4 + j) * E + e0 + el];
  const float bh0 = bhh[e0 + el];
  const float bh1 = bhh[E + e0 + el];
  const float bh2 = bhh[2 * E + e0 + el];

  for (int k = 0; k < K; ++k) {
    const unsigned short* hprev = (k & 1) ? hbuf1 : hbuf0;
    unsigned short* hnext = (k & 1) ? hbuf0 : hbuf1;
    const long gi_base = (long)k * B * N3;

    // ---- prologue staging: GIs (6), tile0 (8), tile1 (8) => 22 in flight
#pragma unroll
    for (int i = 0; i < 6; ++i)
      gll16(GI + gi_base + gi_goff[i], &GIs[(i * 256 + tid) * 8]);
#pragma unroll
    for (int t = 0; t < 2; ++t) {
#pragma unroll
      for (int i = 0; i < 2; ++i)
        gll16(hprev + a_goff[i] + t * 64, &As[t][(i * 256 + tid) * 8]);
#pragma unroll
      for (int i = 0; i < 6; ++i)
        gll16(Whhb + b_goff[i] + t * 64, &Bs[t][(i * 256 + tid) * 8]);
    }

    f32x4 acc[4][3];
#pragma unroll
    for (int m = 0; m < 4; ++m)
#pragma unroll
      for (int g = 0; g < 3; ++g)
        acc[m][g] = (f32x4){0.f, 0.f, 0.f, 0.f};

    for (int kt = 0; kt < NKT; ++kt) {
      // tile kt complete when only next tile's 8 loads remain
      if (kt == NKT - 1) asm volatile("s_waitcnt vmcnt(0)" ::: "memory");
      else               asm volatile("s_waitcnt vmcnt(8)" ::: "memory");
      asm volatile("s_waitcnt lgkmcnt(0)" ::: "memory");  // my reads of buf done
      __builtin_amdgcn_s_barrier();
      asm volatile("" ::: "memory");
      if (kt + 2 < NKT) {
        int tb = (kt + 2) % 3;
        long ko = (long)(kt + 2) * 64;
#pragma unroll
        for (int i = 0; i < 2; ++i)
          gll16(hprev + a_goff[i] + ko, &As[tb][(i * 256 + tid) * 8]);
#pragma unroll
        for (int i = 0; i < 6; ++i)
          gll16(Whhb + b_goff[i] + ko, &Bs[tb][(i * 256 + tid) * 8]);
      }
      const int bi = kt % 3;
      const unsigned short* Ab = As[bi];
      const unsigned short* Bb = Bs[bi];
#pragma unroll
      for (int hh = 0; hh < 2; ++hh) {
        const int c8 = hh * 4 + q;
        const int axo = (c8 ^ axsh) << 3;
        bf16x8 af[4];
#pragma unroll
        for (int m = 0; m < 4; ++m)
          af[m] = *(const bf16x8*)&Ab[(m * 16 + (lane & 15)) * 64 + axo];
#pragma unroll
        for (int g = 0; g < 3; ++g) {
          bf16x8 bv = *(const bf16x8*)&Bb[(g * 64 + el) * 64 + axo];
#pragma unroll
          for (int m = 0; m < 4; ++m)
            acc[m][g] = __builtin_amdgcn_mfma_f32_16x16x32_bf16(
                af[m], bv, acc[m][g], 0, 0, 0);
        }
      }
    }

    // ---- fused gates, fully in-register (GIs landed before last barrier)
#pragma unroll
    for (int m = 0; m < 4; ++m) {
#pragma unroll
      for (int j = 0; j < 4; ++j) {
        int row = m * 16 + q * 4 + j;
        float gi_r = b2f(GIs[row * 192 + el]);
        float gi_z = b2f(GIs[row * 192 + 64 + el]);
        float gi_n = b2f(GIs[row * 192 + 128 + el]);
        float r = sigm(gi_r + acc[m][0][j] + bh0);
        float z = sigm(gi_z + acc[m][1][j] + bh1);
        float n = tanh_f(gi_n + r * (acc[m][2][j] + bh2));
        float hv = (1.f - z) * n + z * hreg[m][j];
        hreg[m][j] = hv;
        Ys[row * 72 + el] = f2b(hv);
      }
    }
    __syncthreads();
    // ---- coalesced write-out of h_next and Y[k] ----
#pragma unroll
    for (int i = 0; i < 2; ++i) {
      int cgl = i * 256 + tid;
      int row = cgl >> 3, cc = cgl & 7;
      u16x8 v = *(const u16x8*)&Ys[row * 72 + cc * 8];
      *(u16x8*)(hnext + (long)(b0 + row) * E + e0 + cc * 8) = v;
      *(u16x8*)(Y + ((long)k * B + b0 + row) * E + e0 + cc * 8) = v;
    }
    // ---- inter-WG barrier (per bt group of net WGs) ----
    if (k + 1 < K) {
      __syncthreads();          // drains vmcnt: stores visible to fence
      if (tid == 0) {
        __threadfence();
        atomicAdd(&bar[bt * 64], 1u);
        unsigned target = (unsigned)(k + 1) * (unsigned)net;
        while (__hip_atomic_load(&bar[bt * 64], __ATOMIC_RELAXED,
                                 __HIP_MEMORY_SCOPE_AGENT) < target)
          __builtin_amdgcn_s_sleep(1);
        __threadfence();
      }
      __syncthreads();
    }
  }
}

// -------------------- pointwise GRU gates (fallback path) -------------
template<int YMODE>
__global__ __launch_bounds__(256)
void gru_pointwise(const unsigned short* __restrict__ GIk,
                   const float* __restrict__ gh,
                   float* __restrict__ h, unsigned short* __restrict__ hbf,
                   unsigned short* __restrict__ Yb,
                   float* __restrict__ out, int k, int B, int E, int K)
{
  long i4 = ((long)blockIdx.x * blockDim.x + threadIdx.x) * 4;
  if (i4 >= (long)B * E) return;
  long b = i4 / E;
  long e = i4 - b * E;
  long g0 = b * 3 * E + e;
  ushort4 ir = *(const ushort4*)(GIk + g0);
  ushort4 iz = *(const ushort4*)(GIk + g0 + E);
  ushort4 in4 = *(const ushort4*)(GIk + g0 + 2 * E);
  float4 hr = *(const float4*)(gh + g0);
  float4 hz = *(const float4*)(gh + g0 + E);
  float4 hn = *(const float4*)(gh + g0 + 2 * E);
  float4 hv = *(const float4*)(h + i4);

  float irf[4] = { b2f(ir.x), b2f(ir.y), b2f(ir.z), b2f(ir.w) };
  float izf[4] = { b2f(iz.x), b2f(iz.y), b2f(iz.z), b2f(iz.w) };
  float inf_[4] = { b2f(in4.x), b2f(in4.y), b2f(in4.z), b2f(in4.w) };
  float hrf[4] = { hr.x, hr.y, hr.z, hr.w };
  float hzf[4] = { hz.x, hz.y, hz.z, hz.w };
  float hnf[4] = { hn.x, hn.y, hn.z, hn.w };
  float hvf[4] = { hv.x, hv.y, hv.z, hv.w };
  float hnew[4];
#pragma unroll
  for (int j = 0; j < 4; ++j) {
    float r = sigm(irf[j] + hrf[j]);
    float z = sigm(izf[j] + hzf[j]);
    float n = tanh_f(inf_[j] + r * hnf[j]);
    hnew[j] = (1.f - z) * n + z * hvf[j];
  }
  *(float4*)(h + i4) = make_float4(hnew[0], hnew[1], hnew[2], hnew[3]);
  ushort4 hb = make_ushort4(f2b(hnew[0]), f2b(hnew[1]), f2b(hnew[2]), f2b(hnew[3]));
  *(ushort4*)(hbf + i4) = hb;
  if (YMODE == 1) {
    *(ushort4*)(Yb + ((long)k * B + b) * E + e) = hb;
  } else {
    float* o = out + (b * E + e) * K + k;
    o[0] = hnew[0]; o[K] = hnew[1]; o[2 * K] = hnew[2]; o[3 * K] = hnew[3];
  }
}

// -------------------- transpose Y (K,B,E) bf16 -> out (B,E,K) fp32 ----
__global__ __launch_bounds__(256)
void transpose_y(const unsigned short* __restrict__ Yv, float* __restrict__ out,
                 int B, int E, int K)
{
  __shared__ float T[64][65];
  int e0 = blockIdx.x * 64;
  int b = blockIdx.y;
  int t = threadIdx.x;
#pragma unroll
  for (int i = 0; i < 4; ++i) {
    int c = i * 256 + t;
    int k = c >> 4, f4 = c & 15;
    long off = ((long)k * B + b) * E + e0 + f4 * 4;
    ushort4 v = *(const ushort4*)(Yv + off);
    T[k][f4 * 4 + 0] = b2f(v.x); T[k][f4 * 4 + 1] = b2f(v.y);
    T[k][f4 * 4 + 2] = b2f(v.z); T[k][f4 * 4 + 3] = b2f(v.w);
  }
  __syncthreads();
#pragma unroll
  for (int i = 0; i < 4; ++i) {
    int c = i * 256 + t;
    int e = c >> 4, f4k = c & 15;
    float4 w;
    w.x = T[f4k * 4 + 0][e];
    w.y = T[f4k * 4 + 1][e];
    w.z = T[f4k * 4 + 2][e];
    w.w = T[f4k * 4 + 3][e];
    *(float4*)(out + ((long)b * E + e0 + e) * K + f4k * 4) = w;
  }
}

// -------------------- host launch -------------------------------------
extern "C" void kernel_launch(void* const* d_in, const int* in_sizes, int n_in,
                              void* d_out, int out_size, void* d_ws, size_t ws_size,
                              hipStream_t stream)
{
  const float* c   = (const float*)d_in[0];
  const float* x   = (const float*)d_in[1];
  const float* Wih = (const float*)d_in[2];
  const float* Whh = (const float*)d_in[3];
  const float* bih = (const float*)d_in[4];
  const float* bhh = (const float*)d_in[5];
  float* out = (float*)d_out;

  long BE = in_sizes[0];
  int E = (int)(sqrtf((float)(in_sizes[2] / 3)) + 0.5f);
  int B = (int)(BE / E);
  int K = (int)(in_sizes[1] / BE);
  int N3 = 3 * E;
  long M_GI = (long)K * B;

  char* w = (char*)d_ws;
  size_t used = 0;
  auto alloc = [&](size_t bytes) -> char* {
    char* p = w + used;
    used += (bytes + 255) & ~(size_t)255;
    return p;
  };
  unsigned short* Wihb  = (unsigned short*)alloc((size_t)N3 * E * 2);
  unsigned short* Whhb  = (unsigned short*)alloc((size_t)N3 * E * 2);
  unsigned short* hb0   = (unsigned short*)alloc((size_t)B * E * 2);
  float* h32            = (float*)alloc((size_t)B * E * 4);
  float* gh             = (float*)alloc((size_t)B * N3 * 4);
  unsigned short* GIstep= (unsigned short*)alloc((size_t)B * N3 * 2);
  unsigned short* XS    = (unsigned short*)alloc((size_t)K * B * E * 2);

  size_t rem = (ws_size > used) ? ws_size - used : 0;
  size_t szHb1 = (((size_t)B * E * 2) + 255) & ~(size_t)255;
  size_t szGI  = (((size_t)K * B * N3 * 2) + 255) & ~(size_t)255;
  size_t szY   = (((size_t)K * B * E * 2) + 255) & ~(size_t)255;
  int nbt = B / 64, net = E / 64;
  int NKT = E / 64;
  size_t szBar = ((size_t)nbt * 64 * 4 + 255) & ~(size_t)255;

  bool canPersist = (B % 64 == 0) && (E % 64 == 0) && (nbt * net == 256) &&
                    (NKT >= 2) && (rem >= szHb1 + szGI + szY + szBar);

  long nW = (long)N3 * E;
  prep_kernel<<<dim3(2048), dim3(256), 0, stream>>>(Wih, Whh, c, Wihb, Whhb,
                                                    hb0, h32, nW, BE);
  hipMemsetAsync(XS, 0, (size_t)B * E * 2, stream);
  transpose_x<<<dim3(E / 64, B), dim3(256), 0, stream>>>(x, XS, B, E, K);

  if (canPersist) {
    unsigned short* hb1 = (unsigned short*)alloc(szHb1);
    unsigned short* GI  = (unsigned short*)alloc(szGI);
    unsigned short* Yb  = (unsigned short*)alloc(szY);
    unsigned int*   bar = (unsigned int*)alloc(szBar);

    gemm_bt<1><<<dim3(N3 / BN, (int)(M_GI / BM)), dim3(256), 0, stream>>>(
        XS, Wihb, bih, nullptr, GI, (int)M_GI, N3, E);
    hipMemsetAsync(bar, 0, szBar, stream);

    const unsigned short* GIc = GI;
    const unsigned short* Whhc = Whhb;
    const float* bhhc = bhh;
    const float* cc = c;
    void* args[] = { (void*)&GIc, (void*)&Whhc, (void*)&bhhc, (void*)&cc,
                     (void*)&hb0, (void*)&hb1, (void*)&Yb,
                     (void*)&bar, (void*)&B, (void*)&E, (void*)&K, (void*)&net };
    hipError_t ce = hipLaunchCooperativeKernel(
        (const void*)gru_rec2, dim3(nbt * net), dim3(256), args, 0, stream);
    if (ce != hipSuccess) {
      (void)hipGetLastError();
      gru_rec2<<<dim3(nbt * net), dim3(256), 0, stream>>>(
          GIc, Whhc, bhhc, cc, hb0, hb1, Yb, bar, B, E, K, net);
    }
    transpose_y<<<dim3(E / 64, B), dim3(256), 0, stream>>>(Yb, out, B, E, K);
    return;
  }

  // -------- fallback: per-step GEMMs (round-1 path) --------
  int haveY = rem >= szY;
  unsigned short* Yb = haveY ? (unsigned short*)alloc(szY) : nullptr;
  int pgrid = (int)((BE / 4 + 255) / 256);
  for (int k = 0; k < K; ++k) {
    gemm_bt<1><<<dim3(N3 / BN, B / BM), dim3(256), 0, stream>>>(
        XS + (size_t)k * B * E, Wihb, bih, nullptr, GIstep, B, N3, E);
    gemm_bt<0><<<dim3(N3 / BN, B / BM), dim3(256), 0, stream>>>(
        hb0, Whhb, bhh, gh, nullptr, B, N3, E);
    if (haveY)
      gru_pointwise<1><<<dim3(pgrid), dim3(256), 0, stream>>>(
          GIstep, gh, h32, hb0, Yb, out, k, B, E, K);
    else
      gru_pointwise<2><<<dim3(pgrid), dim3(256), 0, stream>>>(
          GIstep, gh, h32, hb0, nullptr, out, k, B, E, K);
  }
  if (haveY)
    transpose_y<<<dim3(E / 64, B), dim3(256), 0, stream>>>(Yb, out, B, E, K);
}

// Round 4
// 2111.202 us; speedup vs baseline: 1.4443x; 1.4443x over previous
//
#include <hip/hip_runtime.h>
#include <hip/hip_bf16.h>
#include <math.h>

typedef __bf16 bf16x8 __attribute__((ext_vector_type(8)));
typedef float f32x4 __attribute__((ext_vector_type(4)));
typedef unsigned short u16x8 __attribute__((ext_vector_type(8)));

__device__ inline unsigned short f2b(float f) {
  union { float f; unsigned u; } v; v.f = f;
  unsigned u = v.u;
  return (unsigned short)((u + 0x7fffu + ((u >> 16) & 1u)) >> 16);
}
__device__ inline float b2f(unsigned short s) {
  union { unsigned u; float f; } v; v.u = ((unsigned)s) << 16;
  return v.f;
}
__device__ inline float sigm(float x) { return 1.f / (1.f + __expf(-x)); }
__device__ inline float tanh_f(float x) {
  float e = __expf(2.f * x);
  return 1.f - 2.f / (e + 1.f);
}
__device__ inline void gll16(const unsigned short* g, unsigned short* l) {
  __builtin_amdgcn_global_load_lds(
      (const __attribute__((address_space(1))) void*)g,
      (__attribute__((address_space(3))) void*)l, 16, 0, 0);
}

// -------------------- prep: weights->bf16, h init --------------------
__global__ __launch_bounds__(256) void prep_kernel(
    const float* __restrict__ Wih, const float* __restrict__ Whh,
    const float* __restrict__ c, unsigned short* __restrict__ Wihb,
    unsigned short* __restrict__ Whhb, unsigned short* __restrict__ hbf,
    float* __restrict__ h32, long nW, long nH)
{
  long stride = (long)gridDim.x * blockDim.x;
  long t0 = (long)blockIdx.x * blockDim.x + threadIdx.x;
  for (long i = t0; i < nW; i += stride) {
    Wihb[i] = f2b(Wih[i]);
    Whhb[i] = f2b(Whh[i]);
  }
  for (long i = t0; i < nH; i += stride) {
    float v = c[i];
    h32[i] = v;
    hbf[i] = f2b(v);
  }
}

// ---- reorder rows: row' = (g6*3+g)*64+elo  <-  row = g*E + g6*64 + elo ----
__global__ __launch_bounds__(256) void reorder_kernel(
    const unsigned short* __restrict__ Wihb, const unsigned short* __restrict__ Whhb,
    const float* __restrict__ bih, const float* __restrict__ bhh,
    unsigned short* __restrict__ Wihp, unsigned short* __restrict__ Whhp,
    float* __restrict__ bihp, float* __restrict__ bhhp, int E)
{
  int N3 = 3 * E;
  long total = (long)N3 * E;
  long stride = (long)gridDim.x * blockDim.x;
  long t0 = (long)blockIdx.x * blockDim.x + threadIdx.x;
  for (long i = t0; i < total; i += stride) {
    int rp = (int)(i / E);
    int col = (int)(i - (long)rp * E);
    int g6 = rp / 192, rem = rp - g6 * 192;
    int g = rem >> 6, elo = rem & 63;
    long src = ((long)g * E + g6 * 64 + elo) * E + col;
    Wihp[i] = Wihb[src];
    Whhp[i] = Whhb[src];
  }
  for (long i = t0; i < N3; i += stride) {
    int rp = (int)i;
    int g6 = rp / 192, rem = rp - g6 * 192;
    int g = rem >> 6, elo = rem & 63;
    bihp[i] = bih[(long)g * E + g6 * 64 + elo];
    bhhp[i] = bhh[(long)g * E + g6 * 64 + elo];
  }
}

// -------------------- transpose x (B,E,K) -> XS (K,B,E) bf16 ----------
__global__ __launch_bounds__(256) void transpose_x(
    const float* __restrict__ x, unsigned short* __restrict__ XS,
    int B, int E, int K)
{
  __shared__ float T[64][65];
  int e0 = blockIdx.x * 64;
  int b = blockIdx.y;
  int t = threadIdx.x;
  const float* xb = x + ((long)b * E + e0) * K;
#pragma unroll
  for (int i = 0; i < 4; ++i) {
    int cidx = i * 256 + t;
    int e = cidx >> 4;
    int f4 = cidx & 15;
    float4 v = *(const float4*)(xb + (long)e * K + f4 * 4);
    T[e][f4 * 4 + 0] = v.x;
    T[e][f4 * 4 + 1] = v.y;
    T[e][f4 * 4 + 2] = v.z;
    T[e][f4 * 4 + 3] = v.w;
  }
  __syncthreads();
#pragma unroll
  for (int i = 0; i < 16; ++i) {
    int cidx = i * 256 + t;
    int k = cidx >> 6;
    int e = cidx & 63;
    if (k < K - 1)
      XS[((long)(k + 1) * B + b) * E + e0 + e] = f2b(T[e][k]);
  }
}

// -------------------- GEMM: C(M,N) = A(M,K) @ Bw(N,K)^T + bias --------
#define BM 128
#define BN 128
#define BKS 64

template<int OUTBF>
__global__ __launch_bounds__(256)
void gemm_bt(const unsigned short* __restrict__ A,
             const unsigned short* __restrict__ Bw,
             const float* __restrict__ bias,
             float* __restrict__ Cf, unsigned short* __restrict__ Cb,
             int M, int N, int K)
{
  __shared__ __align__(16) unsigned short As[BM * BKS];
  __shared__ __align__(16) unsigned short Bs[BN * BKS];

  int nwg = gridDim.x * gridDim.y;
  int wg = blockIdx.y * gridDim.x + blockIdx.x;
  if ((nwg & 7) == 0) { int ch = nwg >> 3; wg = (wg & 7) * ch + (wg >> 3); }
  int tx = wg % gridDim.x;
  int ty = wg / gridDim.x;

  const int tid = threadIdx.x;
  const int lane = tid & 63;
  const int wave = tid >> 6;
  const int wr = wave >> 1, wc = wave & 1;

  f32x4 acc[4][4] = {};

  const long a_base = (long)ty * BM * K;
  const long b_base = (long)tx * BN * K;

  for (int kt = 0; kt < K; kt += BKS) {
    __syncthreads();
#pragma unroll
    for (int i = 0; i < 4; ++i) {
      int c = i * 256 + tid;
      int row = c >> 3, sc = c & 7;
      int gcol8 = sc ^ (row & 7);
      const unsigned short* ga = A + a_base + (long)row * K + kt + gcol8 * 8;
      const unsigned short* gb = Bw + b_base + (long)row * K + kt + gcol8 * 8;
      int cbase = (i * 256 + wave * 64) * 8;
      gll16(ga, &As[cbase]);
      gll16(gb, &Bs[cbase]);
    }
    __syncthreads();
#pragma unroll
    for (int kk = 0; kk < BKS; kk += 32) {
      int kidx = kk + ((lane >> 4) << 3);
      int c8 = kidx >> 3;
      bf16x8 af[4], bfv[4];
#pragma unroll
      for (int m = 0; m < 4; ++m) {
        int row = wr * 64 + m * 16 + (lane & 15);
        af[m] = *(const bf16x8*)&As[row * BKS + ((c8 ^ (row & 7)) << 3)];
      }
#pragma unroll
      for (int n = 0; n < 4; ++n) {
        int col = wc * 64 + n * 16 + (lane & 15);
        bfv[n] = *(const bf16x8*)&Bs[col * BKS + ((c8 ^ (col & 7)) << 3)];
      }
#pragma unroll
      for (int m = 0; m < 4; ++m)
#pragma unroll
        for (int n = 0; n < 4; ++n)
          acc[m][n] = __builtin_amdgcn_mfma_f32_16x16x32_bf16(
              af[m], bfv[n], acc[m][n], 0, 0, 0);
    }
  }

  long crow0 = (long)ty * BM + wr * 64;
  long ccol0 = (long)tx * BN + wc * 64;
#pragma unroll
  for (int m = 0; m < 4; ++m) {
#pragma unroll
    for (int n = 0; n < 4; ++n) {
      long col = ccol0 + n * 16 + (lane & 15);
      float bv = bias[col];
#pragma unroll
      for (int j = 0; j < 4; ++j) {
        long row = crow0 + m * 16 + ((lane >> 4) << 2) + j;
        float v = acc[m][n][j] + bv;
        if (OUTBF) Cb[row * N + col] = f2b(v);
        else       Cf[row * N + col] = v;
      }
    }
  }
}

// -------------------- fused GRU step (one launch per k) ---------------
// grid (E/64, B/64), 256 thr. WG (bt,e6): 64 b-rows x 64 e-cols, all 3
// gates. Whp: reordered (3E,E), WG panel = contiguous rows [e6*192,+192).
// GIk: (B,3E) reordered cols. h32 fp32 in-place; hin/hout bf16 ping-pong.
__global__ __launch_bounds__(256, 1)
void gru_step(const unsigned short* __restrict__ GIk,
              const unsigned short* __restrict__ Whp,
              const float* __restrict__ bhp,
              float* __restrict__ h32,
              const unsigned short* __restrict__ hin,
              unsigned short* __restrict__ hout,
              unsigned short* __restrict__ Yk,
              int B, int E)
{
  __shared__ __align__(16) unsigned short As[3][4096];    // 64x64 bf16 x3
  __shared__ __align__(16) unsigned short Bs[3][12288];   // 192x64 bf16 x3
  __shared__ __align__(16) unsigned short GIs[12288];     // 64x192 bf16
  __shared__ __align__(16) unsigned short Ys[64 * 72];    // 64x64 padded

  const int N3 = 3 * E;
  const int NKT = E >> 6;
  const int e6 = blockIdx.x;           // wg%8 == e6%8 -> panel sharers same XCD
  const int bt = blockIdx.y;
  const int b0 = bt << 6;
  const int ec0 = e6 * 192;
  const int tid = threadIdx.x;
  const int lane = tid & 63;
  const int q = lane >> 4;
  const int el = ((tid >> 6) << 4) + (lane & 15);
  const int axsh = lane & 7;

  // ---- staging offsets ----
  long a_goff[2];
#pragma unroll
  for (int i = 0; i < 2; ++i) {
    int cgl = i * 256 + tid;
    int row = cgl >> 3;
    int g8 = (cgl & 7) ^ (row & 7);
    a_goff[i] = (long)(b0 + row) * E + g8 * 8;
  }
  long b_goff[6];
#pragma unroll
  for (int i = 0; i < 6; ++i) {
    int cgl = i * 256 + tid;
    int row = cgl >> 3;
    int g8 = (cgl & 7) ^ (row & 7);
    b_goff[i] = (long)(ec0 + row) * E + g8 * 8;
  }
  long gi_goff[6];
#pragma unroll
  for (int i = 0; i < 6; ++i) {
    int cgl = i * 256 + tid;
    int row = cgl / 24;
    int cc = cgl - row * 24;
    gi_goff[i] = (long)(b0 + row) * N3 + ec0 + cc * 8;
  }

  // ---- prologue staging: tile0 (8), tile1 (8), GI (6) ----
#pragma unroll
  for (int i = 0; i < 2; ++i) gll16(hin + a_goff[i], &As[0][(i * 256 + tid) * 8]);
#pragma unroll
  for (int i = 0; i < 6; ++i) gll16(Whp + b_goff[i], &Bs[0][(i * 256 + tid) * 8]);
#pragma unroll
  for (int i = 0; i < 2; ++i) gll16(hin + a_goff[i] + 64, &As[1][(i * 256 + tid) * 8]);
#pragma unroll
  for (int i = 0; i < 6; ++i) gll16(Whp + b_goff[i] + 64, &Bs[1][(i * 256 + tid) * 8]);
#pragma unroll
  for (int i = 0; i < 6; ++i) gll16(GIk + gi_goff[i], &GIs[(i * 256 + tid) * 8]);

  // ---- persistent per-lane state ----
  float hreg[4][4];
#pragma unroll
  for (int m = 0; m < 4; ++m)
#pragma unroll
    for (int j = 0; j < 4; ++j)
      hreg[m][j] = h32[(long)(b0 + m * 16 + q * 4 + j) * E + (e6 << 6) + el];
  const float bh0 = bhp[ec0 + el];
  const float bh1 = bhp[ec0 + 64 + el];
  const float bh2 = bhp[ec0 + 128 + el];

  f32x4 acc[4][3];
#pragma unroll
  for (int m = 0; m < 4; ++m)
#pragma unroll
    for (int g = 0; g < 3; ++g)
      acc[m][g] = (f32x4){0.f, 0.f, 0.f, 0.f};

  for (int kt = 0; kt < NKT; ++kt) {
    if (kt == NKT - 1)  asm volatile("s_waitcnt vmcnt(0)" ::: "memory");
    else if (kt < 2)    asm volatile("s_waitcnt vmcnt(14)" ::: "memory");
    else                asm volatile("s_waitcnt vmcnt(8)" ::: "memory");
    asm volatile("s_waitcnt lgkmcnt(0)" ::: "memory");
    __builtin_amdgcn_s_barrier();
    asm volatile("" ::: "memory");
    if (kt + 2 < NKT) {
      int tb = (kt + 2) % 3;
      long ko = (long)(kt + 2) * 64;
#pragma unroll
      for (int i = 0; i < 2; ++i)
        gll16(hin + a_goff[i] + ko, &As[tb][(i * 256 + tid) * 8]);
#pragma unroll
      for (int i = 0; i < 6; ++i)
        gll16(Whp + b_goff[i] + ko, &Bs[tb][(i * 256 + tid) * 8]);
    }
    const int bi = kt % 3;
    const unsigned short* Ab = As[bi];
    const unsigned short* Bb = Bs[bi];
#pragma unroll
    for (int hh = 0; hh < 2; ++hh) {
      const int c8 = hh * 4 + q;
      const int axo = (c8 ^ axsh) << 3;
      bf16x8 af[4];
#pragma unroll
      for (int m = 0; m < 4; ++m)
        af[m] = *(const bf16x8*)&Ab[(m * 16 + (lane & 15)) * 64 + axo];
#pragma unroll
      for (int g = 0; g < 3; ++g) {
        bf16x8 bv = *(const bf16x8*)&Bb[(g * 64 + el) * 64 + axo];
#pragma unroll
        for (int m = 0; m < 4; ++m)
          acc[m][g] = __builtin_amdgcn_mfma_f32_16x16x32_bf16(
              af[m], bv, acc[m][g], 0, 0, 0);
      }
    }
  }

  // ---- fused gates (GIs resident; vmcnt(0) done at last tile) ----
#pragma unroll
  for (int m = 0; m < 4; ++m) {
#pragma unroll
    for (int j = 0; j < 4; ++j) {
      int row = m * 16 + q * 4 + j;
      float gi_r = b2f(GIs[row * 192 + el]);
      float gi_z = b2f(GIs[row * 192 + 64 + el]);
      float gi_n = b2f(GIs[row * 192 + 128 + el]);
      float r = sigm(gi_r + acc[m][0][j] + bh0);
      float z = sigm(gi_z + acc[m][1][j] + bh1);
      float n = tanh_f(gi_n + r * (acc[m][2][j] + bh2));
      float hv = (1.f - z) * n + z * hreg[m][j];
      h32[(long)(b0 + row) * E + (e6 << 6) + el] = hv;
      Ys[row * 72 + el] = f2b(hv);
    }
  }
  __syncthreads();
  // ---- coalesced write-out of h_next and Y[k] ----
#pragma unroll
  for (int i = 0; i < 2; ++i) {
    int cgl = i * 256 + tid;
    int row = cgl >> 3, cc = cgl & 7;
    u16x8 v = *(const u16x8*)&Ys[row * 72 + cc * 8];
    *(u16x8*)(hout + (long)(b0 + row) * E + (e6 << 6) + cc * 8) = v;
    *(u16x8*)(Yk + (long)(b0 + row) * E + (e6 << 6) + cc * 8) = v;
  }
}

// -------------------- pointwise GRU gates (fallback path) -------------
template<int YMODE>
__global__ __launch_bounds__(256)
void gru_pointwise(const unsigned short* __restrict__ GIk,
                   const float* __restrict__ gh,
                   float* __restrict__ h, unsigned short* __restrict__ hbf,
                   unsigned short* __restrict__ Yb,
                   float* __restrict__ out, int k, int B, int E, int K)
{
  long i4 = ((long)blockIdx.x * blockDim.x + threadIdx.x) * 4;
  if (i4 >= (long)B * E) return;
  long b = i4 / E;
  long e = i4 - b * E;
  long g0 = b * 3 * E + e;
  ushort4 ir = *(const ushort4*)(GIk + g0);
  ushort4 iz = *(const ushort4*)(GIk + g0 + E);
  ushort4 in4 = *(const ushort4*)(GIk + g0 + 2 * E);
  float4 hr = *(const float4*)(gh + g0);
  float4 hz = *(const float4*)(gh + g0 + E);
  float4 hn = *(const float4*)(gh + g0 + 2 * E);
  float4 hv = *(const float4*)(h + i4);

  float irf[4] = { b2f(ir.x), b2f(ir.y), b2f(ir.z), b2f(ir.w) };
  float izf[4] = { b2f(iz.x), b2f(iz.y), b2f(iz.z), b2f(iz.w) };
  float inf_[4] = { b2f(in4.x), b2f(in4.y), b2f(in4.z), b2f(in4.w) };
  float hrf[4] = { hr.x, hr.y, hr.z, hr.w };
  float hzf[4] = { hz.x, hz.y, hz.z, hz.w };
  float hnf[4] = { hn.x, hn.y, hn.z, hn.w };
  float hvf[4] = { hv.x, hv.y, hv.z, hv.w };
  float hnew[4];
#pragma unroll
  for (int j = 0; j < 4; ++j) {
    float r = sigm(irf[j] + hrf[j]);
    float z = sigm(izf[j] + hzf[j]);
    float n = tanh_f(inf_[j] + r * hnf[j]);
    hnew[j] = (1.f - z) * n + z * hvf[j];
  }
  *(float4*)(h + i4) = make_float4(hnew[0], hnew[1], hnew[2], hnew[3]);
  ushort4 hb = make_ushort4(f2b(hnew[0]), f2b(hnew[1]), f2b(hnew[2]), f2b(hnew[3]));
  *(ushort4*)(hbf + i4) = hb;
  if (YMODE == 1) {
    *(ushort4*)(Yb + ((long)k * B + b) * E + e) = hb;
  } else {
    float* o = out + (b * E + e) * K + k;
    o[0] = hnew[0]; o[K] = hnew[1]; o[2 * K] = hnew[2]; o[3 * K] = hnew[3];
  }
}

// -------------------- transpose Y (K,B,E) bf16 -> out (B,E,K) fp32 ----
__global__ __launch_bounds__(256)
void transpose_y(const unsigned short* __restrict__ Yv, float* __restrict__ out,
                 int B, int E, int K)
{
  __shared__ float T[64][65];
  int e0 = blockIdx.x * 64;
  int b = blockIdx.y;
  int t = threadIdx.x;
#pragma unroll
  for (int i = 0; i < 4; ++i) {
    int c = i * 256 + t;
    int k = c >> 4, f4 = c & 15;
    long off = ((long)k * B + b) * E + e0 + f4 * 4;
    ushort4 v = *(const ushort4*)(Yv + off);
    T[k][f4 * 4 + 0] = b2f(v.x); T[k][f4 * 4 + 1] = b2f(v.y);
    T[k][f4 * 4 + 2] = b2f(v.z); T[k][f4 * 4 + 3] = b2f(v.w);
  }
  __syncthreads();
#pragma unroll
  for (int i = 0; i < 4; ++i) {
    int c = i * 256 + t;
    int e = c >> 4, f4k = c & 15;
    float4 w;
    w.x = T[f4k * 4 + 0][e];
    w.y = T[f4k * 4 + 1][e];
    w.z = T[f4k * 4 + 2][e];
    w.w = T[f4k * 4 + 3][e];
    *(float4*)(out + ((long)b * E + e0 + e) * K + f4k * 4) = w;
  }
}

// -------------------- host launch -------------------------------------
extern "C" void kernel_launch(void* const* d_in, const int* in_sizes, int n_in,
                              void* d_out, int out_size, void* d_ws, size_t ws_size,
                              hipStream_t stream)
{
  const float* c   = (const float*)d_in[0];
  const float* x   = (const float*)d_in[1];
  const float* Wih = (const float*)d_in[2];
  const float* Whh = (const float*)d_in[3];
  const float* bih = (const float*)d_in[4];
  const float* bhh = (const float*)d_in[5];
  float* out = (float*)d_out;

  long BE = in_sizes[0];
  int E = (int)(sqrtf((float)(in_sizes[2] / 3)) + 0.5f);
  int B = (int)(BE / E);
  int K = (int)(in_sizes[1] / BE);
  int N3 = 3 * E;
  long M_GI = (long)K * B;

  char* w = (char*)d_ws;
  size_t used = 0;
  auto alloc = [&](size_t bytes) -> char* {
    char* p = w + used;
    used += (bytes + 255) & ~(size_t)255;
    return p;
  };
  unsigned short* Wihb  = (unsigned short*)alloc((size_t)N3 * E * 2);
  unsigned short* Whhb  = (unsigned short*)alloc((size_t)N3 * E * 2);
  unsigned short* hb0   = (unsigned short*)alloc((size_t)B * E * 2);
  float* h32            = (float*)alloc((size_t)B * E * 4);
  float* gh             = (float*)alloc((size_t)B * N3 * 4);
  unsigned short* GIstep= (unsigned short*)alloc((size_t)B * N3 * 2);
  unsigned short* XS    = (unsigned short*)alloc((size_t)K * B * E * 2);

  size_t rem = (ws_size > used) ? ws_size - used : 0;
  size_t szW   = (((size_t)N3 * E * 2) + 255) & ~(size_t)255;
  size_t szB3  = (((size_t)N3 * 4) + 255) & ~(size_t)255;
  size_t szHb1 = (((size_t)B * E * 2) + 255) & ~(size_t)255;
  size_t szGI  = (((size_t)K * B * N3 * 2) + 255) & ~(size_t)255;
  size_t szY   = (((size_t)K * B * E * 2) + 255) & ~(size_t)255;
  int nbt = B / 64, net = E / 64;
  int NKT = E / 64;

  bool canFused = (B % 64 == 0) && (E % 64 == 0) && (NKT >= 2) &&
                  (rem >= 2 * szW + 2 * szB3 + szHb1 + szGI + szY);

  long nW = (long)N3 * E;
  prep_kernel<<<dim3(2048), dim3(256), 0, stream>>>(Wih, Whh, c, Wihb, Whhb,
                                                    hb0, h32, nW, BE);
  hipMemsetAsync(XS, 0, (size_t)B * E * 2, stream);
  transpose_x<<<dim3(E / 64, B), dim3(256), 0, stream>>>(x, XS, B, E, K);

  if (canFused) {
    unsigned short* Wihp = (unsigned short*)alloc(szW);
    unsigned short* Whhp = (unsigned short*)alloc(szW);
    float* bihp          = (float*)alloc(szB3);
    float* bhhp          = (float*)alloc(szB3);
    unsigned short* hb1  = (unsigned short*)alloc(szHb1);
    unsigned short* GI   = (unsigned short*)alloc(szGI);
    unsigned short* Yb   = (unsigned short*)alloc(szY);

    reorder_kernel<<<dim3(2048), dim3(256), 0, stream>>>(
        Wihb, Whhb, bih, bhh, Wihp, Whhp, bihp, bhhp, E);

    gemm_bt<1><<<dim3(N3 / BN, (int)(M_GI / BM)), dim3(256), 0, stream>>>(
        XS, Wihp, bihp, nullptr, GI, (int)M_GI, N3, E);

    for (int k = 0; k < K; ++k) {
      const unsigned short* hin = (k & 1) ? hb1 : hb0;
      unsigned short* hout = (k & 1) ? hb0 : hb1;
      gru_step<<<dim3(net, nbt), dim3(256), 0, stream>>>(
          GI + (size_t)k * B * N3, Whhp, bhhp, h32, hin, hout,
          Yb + (size_t)k * B * E, B, E);
    }
    transpose_y<<<dim3(E / 64, B), dim3(256), 0, stream>>>(Yb, out, B, E, K);
    return;
  }

  // -------- fallback: per-step GEMMs (round-1 path, normal layout) -----
  int haveY = rem >= szY;
  unsigned short* Yb = haveY ? (unsigned short*)alloc(szY) : nullptr;
  int pgrid = (int)((BE / 4 + 255) / 256);
  for (int k = 0; k < K; ++k) {
    gemm_bt<1><<<dim3(N3 / BN, B / BM), dim3(256), 0, stream>>>(
        XS + (size_t)k * B * E, Wihb, bih, nullptr, GIstep, B, N3, E);
    gemm_bt<0><<<dim3(N3 / BN, B / BM), dim3(256), 0, stream>>>(
        hb0, Whhb, bhh, gh, nullptr, B, N3, E);
    if (haveY)
      gru_pointwise<1><<<dim3(pgrid), dim3(256), 0, stream>>>(
          GIstep, gh, h32, hb0, Yb, out, k, B, E, K);
    else
      gru_pointwise<2><<<dim3(pgrid), dim3(256), 0, stream>>>(
          GIstep, gh, h32, hb0, nullptr, out, k, B, E, K);
  }
  if (haveY)
    transpose_y<<<dim3(E / 64, B), dim3(256), 0, stream>>>(Yb, out, B, E, K);
}